// Round 8
// baseline (88.236 us; speedup 1.0000x reference)
//
#include <hip/hip_runtime.h>

// Ordered product of 4,194,304 (+1 repeat) 2x2 float32 matrices; out = e0^T * M.
// float4 = row-major 2x2: (x y ; z w).
//
// Single fused kernel = R7's phase-1 (1024 blocks x 512 threads, 8 contiguous
// tokens/thread, LDS-staged 2 KB table, DPP/swizzle ordered wave reduce) plus
// a no-wait ticket finisher: each block publishes its partial with agent-scope
// stores and takes a ticket; the LAST block to finish (no spinning, so no
// co-residency requirement) reduces the 1024 partials and writes the output.
// The ticket's initial value is the harness's 0xAA d_ws poison, re-applied
// before every replay, so no init node is needed.

#define T_TOKENS 4194304
#define TPB      512
#define TOKS     8                                   // tokens per thread
#define BLOCKS   (T_TOKENS / (TPB * TOKS))           // 1024
#define POISON   0xAAAAAAAAu
#define LAST_TICKET (POISON + (unsigned)(BLOCKS - 1))

__device__ __forceinline__ float4 mm(const float4 A, const float4 B) {
    float4 C;
    C.x = fmaf(A.x, B.x, A.y * B.z);
    C.y = fmaf(A.x, B.y, A.y * B.w);
    C.z = fmaf(A.z, B.x, A.w * B.z);
    C.w = fmaf(A.z, B.y, A.w * B.w);
    return C;
}

// lane i <- lane i+N within each 16-lane DPP row (row_shr:N). Lanes whose
// source crosses the row keep their own value; the tree never consumes them.
template <int N>
__device__ __forceinline__ float4 dpp_shr4(const float4 m) {
    float4 o;
    o.x = __int_as_float(__builtin_amdgcn_update_dpp(
        __float_as_int(m.x), __float_as_int(m.x), 0x110 | N, 0xF, 0xF, false));
    o.y = __int_as_float(__builtin_amdgcn_update_dpp(
        __float_as_int(m.y), __float_as_int(m.y), 0x110 | N, 0xF, 0xF, false));
    o.z = __int_as_float(__builtin_amdgcn_update_dpp(
        __float_as_int(m.z), __float_as_int(m.z), 0x110 | N, 0xF, 0xF, false));
    o.w = __int_as_float(__builtin_amdgcn_update_dpp(
        __float_as_int(m.w), __float_as_int(m.w), 0x110 | N, 0xF, 0xF, false));
    return o;
}

// lane i <- lane i^XMASK via ds_swizzle (BitMode: offset = xor<<10 | 0x1F).
// For consuming lanes j aligned to 2*XMASK, j^XMASK == j+XMASK (shfl_down).
template <int XMASK>
__device__ __forceinline__ float4 swz_xor4(const float4 m) {
    constexpr int OFF = (XMASK << 10) | 0x1F;
    float4 o;
    o.x = __int_as_float(__builtin_amdgcn_ds_swizzle(__float_as_int(m.x), OFF));
    o.y = __int_as_float(__builtin_amdgcn_ds_swizzle(__float_as_int(m.y), OFF));
    o.z = __int_as_float(__builtin_amdgcn_ds_swizzle(__float_as_int(m.z), OFF));
    o.w = __int_as_float(__builtin_amdgcn_ds_swizzle(__float_as_int(m.w), OFF));
    return o;
}

// Ordered wave reduce (left operand = lower lane = earlier tokens).
__device__ __forceinline__ float4 wave_reduce_mm(float4 m) {
    m = mm(m, dpp_shr4<1>(m));
    m = mm(m, dpp_shr4<2>(m));
    m = mm(m, dpp_shr4<4>(m));
    m = mm(m, dpp_shr4<8>(m));
    m = mm(m, swz_xor4<16>(m));
    m = mm(m, swz_xor4<32>(m));
    return m;
}

union f4u2 { float4 f; unsigned long long u[2]; };

__global__ __launch_bounds__(TPB) void scan_fused(const int4* __restrict__ tok4,
                                                  const float4* __restrict__ ls,
                                                  const int* __restrict__ tokens,
                                                  float* __restrict__ out,
                                                  unsigned long long* __restrict__ pz,
                                                  unsigned* __restrict__ ticket) {
    __shared__ float4 s_ls[128];          // 2 KB staged transition table
    __shared__ float4 sm[8];
    __shared__ unsigned my_ticket;

    const int tid = threadIdx.x;
    const int b   = blockIdx.x;
    if (tid < 128) s_ls[tid] = ls[tid];
    __syncthreads();

    const int g  = b * TPB + tid;
    const int4 a = tok4[2 * g];
    const int4 c = tok4[2 * g + 1];

    float4 m = s_ls[a.x];                 // ds_read_b128 gathers
    m = mm(m, s_ls[a.y]);
    m = mm(m, s_ls[a.z]);
    m = mm(m, s_ls[a.w]);
    m = mm(m, s_ls[c.x]);
    m = mm(m, s_ls[c.y]);
    m = mm(m, s_ls[c.z]);
    m = mm(m, s_ls[c.w]);

    m = wave_reduce_mm(m);                // lane 0 of each wave: wave product

    if ((tid & 63) == 0) sm[tid >> 6] = m;
    __syncthreads();

    if (tid == 0) {
        const float4 q01 = mm(sm[0], sm[1]);
        const float4 q23 = mm(sm[2], sm[3]);
        const float4 q45 = mm(sm[4], sm[5]);
        const float4 q67 = mm(sm[6], sm[7]);
        f4u2 v;
        v.f = mm(mm(q01, q23), mm(q45, q67));
        __hip_atomic_store(&pz[2 * b + 0], v.u[0], __ATOMIC_RELAXED,
                           __HIP_MEMORY_SCOPE_AGENT);
        __hip_atomic_store(&pz[2 * b + 1], v.u[1], __ATOMIC_RELAXED,
                           __HIP_MEMORY_SCOPE_AGENT);
        // acq_rel: orders the partial stores before the ticket increment and
        // makes all earlier blocks' partials visible to the last ticket-holder.
        my_ticket = __hip_atomic_fetch_add(ticket, 1u, __ATOMIC_ACQ_REL,
                                           __HIP_MEMORY_SCOPE_AGENT);
    }
    __syncthreads();
    if (my_ticket != LAST_TICKET) return;   // block-uniform; only last block stays

    // ---- finisher: 512 threads, 2 consecutive partials each ----
    f4u2 q0, q1;
    q0.u[0] = __hip_atomic_load(&pz[4 * tid + 0], __ATOMIC_RELAXED,
                                __HIP_MEMORY_SCOPE_AGENT);
    q0.u[1] = __hip_atomic_load(&pz[4 * tid + 1], __ATOMIC_RELAXED,
                                __HIP_MEMORY_SCOPE_AGENT);
    q1.u[0] = __hip_atomic_load(&pz[4 * tid + 2], __ATOMIC_RELAXED,
                                __HIP_MEMORY_SCOPE_AGENT);
    q1.u[1] = __hip_atomic_load(&pz[4 * tid + 3], __ATOMIC_RELAXED,
                                __HIP_MEMORY_SCOPE_AGENT);
    float4 acc = mm(q0.f, q1.f);

    acc = wave_reduce_mm(acc);

    __shared__ float4 sf[8];
    if ((tid & 63) == 0) sf[tid >> 6] = acc;
    __syncthreads();
    if (tid == 0) {
        const float4 r01 = mm(sf[0], sf[1]);
        const float4 r23 = mm(sf[2], sf[3]);
        const float4 r45 = mm(sf[4], sf[5]);
        const float4 r67 = mm(sf[6], sf[7]);
        float4 M = mm(mm(r01, r23), mm(r45, r67));
        M = mm(M, s_ls[tokens[T_TOKENS - 1]]);   // last token applied twice
        out[0] = M.x;
        out[1] = M.y;
    }
}

extern "C" void kernel_launch(void* const* d_in, const int* in_sizes, int n_in,
                              void* d_out, int out_size, void* d_ws, size_t ws_size,
                              hipStream_t stream) {
    const int*    tokens = (const int*)d_in[0];     // (T,) int32
    const float4* ls     = (const float4*)d_in[1];  // (128,2,2) f32 == 128 x float4
    float* out = (float*)d_out;                     // 2 floats

    unsigned long long* pz = (unsigned long long*)d_ws;        // 1024 x 16 B
    unsigned* ticket = (unsigned*)((char*)d_ws + BLOCKS * 16); // poison = 0xAAAAAAAA

    scan_fused<<<BLOCKS, TPB, 0, stream>>>((const int4*)tokens, ls, tokens, out,
                                           pz, ticket);
}

// Round 9
// 68.165 us; speedup vs baseline: 1.2945x; 1.2945x over previous
//
#include <hip/hip_runtime.h>

// Ordered product of 4,194,304 (+1 repeat) 2x2 float32 matrices; out = e0^T * M.
// float4 = row-major 2x2: (x y ; z w).
//
// Two-kernel tree reduction (fusion with agent-scope sync measured +20us three
// times -> abandoned). Phase 1: 512 blocks x 512 threads, 16 contiguous
// tokens/thread, LDS-staged 2 KB table, DPP/swizzle ordered wave reduce.
// mm() is written row-wise on <2 x float> so the backend can emit
// v_pk_fma_f32 (4 packed ops instead of 8 scalar per 2x2 multiply).

#define T_TOKENS 4194304
#define TPB      512
#define TOKS     16                                  // tokens per thread
#define BLOCKS   (T_TOKENS / (TPB * TOKS))           // 512

typedef float v2f __attribute__((ext_vector_type(2)));

__device__ __forceinline__ float4 mm(const float4 A, const float4 B) {
    const v2f Br0 = {B.x, B.y};
    const v2f Br1 = {B.z, B.w};
    const v2f c0 = A.x * Br0 + A.y * Br1;   // -> v_pk_fma_f32 candidates
    const v2f c1 = A.z * Br0 + A.w * Br1;
    return make_float4(c0.x, c0.y, c1.x, c1.y);
}

// lane i <- lane i+N within each 16-lane DPP row (row_shr:N). Lanes whose
// source crosses the row keep their own value; the tree never consumes them.
template <int N>
__device__ __forceinline__ float4 dpp_shr4(const float4 m) {
    float4 o;
    o.x = __int_as_float(__builtin_amdgcn_update_dpp(
        __float_as_int(m.x), __float_as_int(m.x), 0x110 | N, 0xF, 0xF, false));
    o.y = __int_as_float(__builtin_amdgcn_update_dpp(
        __float_as_int(m.y), __float_as_int(m.y), 0x110 | N, 0xF, 0xF, false));
    o.z = __int_as_float(__builtin_amdgcn_update_dpp(
        __float_as_int(m.z), __float_as_int(m.z), 0x110 | N, 0xF, 0xF, false));
    o.w = __int_as_float(__builtin_amdgcn_update_dpp(
        __float_as_int(m.w), __float_as_int(m.w), 0x110 | N, 0xF, 0xF, false));
    return o;
}

// lane i <- lane i^XMASK via ds_swizzle (BitMode: offset = xor<<10 | 0x1F).
// For consuming lanes j aligned to 2*XMASK, j^XMASK == j+XMASK (shfl_down).
template <int XMASK>
__device__ __forceinline__ float4 swz_xor4(const float4 m) {
    constexpr int OFF = (XMASK << 10) | 0x1F;
    float4 o;
    o.x = __int_as_float(__builtin_amdgcn_ds_swizzle(__float_as_int(m.x), OFF));
    o.y = __int_as_float(__builtin_amdgcn_ds_swizzle(__float_as_int(m.y), OFF));
    o.z = __int_as_float(__builtin_amdgcn_ds_swizzle(__float_as_int(m.z), OFF));
    o.w = __int_as_float(__builtin_amdgcn_ds_swizzle(__float_as_int(m.w), OFF));
    return o;
}

// Ordered wave reduce (left operand = lower lane = earlier tokens): after
// round s, lane j (j % 2s == 0) holds the product of segment [j, j+2s).
__device__ __forceinline__ float4 wave_reduce_mm(float4 m) {
    m = mm(m, dpp_shr4<1>(m));
    m = mm(m, dpp_shr4<2>(m));
    m = mm(m, dpp_shr4<4>(m));
    m = mm(m, dpp_shr4<8>(m));
    m = mm(m, swz_xor4<16>(m));
    m = mm(m, swz_xor4<32>(m));
    return m;
}

// Phase 1: 512 blocks x 512 threads (8 waves), 16 tokens/thread.
__global__ __launch_bounds__(TPB) void scan_phase1(const int4* __restrict__ tok4,
                                                   const float4* __restrict__ ls,
                                                   float4* __restrict__ partials) {
    __shared__ float4 s_ls[128];          // 2 KB staged transition table
    __shared__ float4 sm[8];

    const int tid = threadIdx.x;
    if (tid < 128) s_ls[tid] = ls[tid];
    __syncthreads();

    const int4* p = tok4 + (size_t)(blockIdx.x * TPB + tid) * (TOKS / 4);
    const int4 t0 = p[0];
    const int4 t1 = p[1];
    const int4 t2 = p[2];
    const int4 t3 = p[3];

    float4 m = s_ls[t0.x];                // ds_read_b128 gathers
    m = mm(m, s_ls[t0.y]);
    m = mm(m, s_ls[t0.z]);
    m = mm(m, s_ls[t0.w]);
    m = mm(m, s_ls[t1.x]);
    m = mm(m, s_ls[t1.y]);
    m = mm(m, s_ls[t1.z]);
    m = mm(m, s_ls[t1.w]);
    m = mm(m, s_ls[t2.x]);
    m = mm(m, s_ls[t2.y]);
    m = mm(m, s_ls[t2.z]);
    m = mm(m, s_ls[t2.w]);
    m = mm(m, s_ls[t3.x]);
    m = mm(m, s_ls[t3.y]);
    m = mm(m, s_ls[t3.z]);
    m = mm(m, s_ls[t3.w]);

    m = wave_reduce_mm(m);                // lane 0 of each wave: wave product

    if ((tid & 63) == 0) sm[tid >> 6] = m;
    __syncthreads();
    if (tid == 0) {
        const float4 q01 = mm(sm[0], sm[1]);
        const float4 q23 = mm(sm[2], sm[3]);
        const float4 q45 = mm(sm[4], sm[5]);
        const float4 q67 = mm(sm[6], sm[7]);
        partials[blockIdx.x] = mm(mm(q01, q23), mm(q45, q67));
    }
}

// Phase 2: one 512-thread block, one partial per thread, ordered reduce,
// apply the doubled last-token matrix, write row 0 (v0 = [1,0]).
__global__ __launch_bounds__(TPB) void scan_phase2(const float4* __restrict__ partials,
                                                   const int* __restrict__ tokens,
                                                   const float4* __restrict__ ls,
                                                   float* __restrict__ out) {
    const int tid = threadIdx.x;
    float4 m = partials[tid];             // coalesced

    m = wave_reduce_mm(m);

    __shared__ float4 sf[8];
    if ((tid & 63) == 0) sf[tid >> 6] = m;
    __syncthreads();
    if (tid == 0) {
        const float4 q01 = mm(sf[0], sf[1]);
        const float4 q23 = mm(sf[2], sf[3]);
        const float4 q45 = mm(sf[4], sf[5]);
        const float4 q67 = mm(sf[6], sf[7]);
        float4 M = mm(mm(q01, q23), mm(q45, q67));
        M = mm(M, ls[tokens[T_TOKENS - 1]]);   // last token applied twice
        out[0] = M.x;
        out[1] = M.y;
    }
}

extern "C" void kernel_launch(void* const* d_in, const int* in_sizes, int n_in,
                              void* d_out, int out_size, void* d_ws, size_t ws_size,
                              hipStream_t stream) {
    const int*    tokens = (const int*)d_in[0];     // (T,) int32
    const float4* ls     = (const float4*)d_in[1];  // (128,2,2) f32 == 128 x float4
    float*  out      = (float*)d_out;               // 2 floats
    float4* partials = (float4*)d_ws;               // 512 * 16 B = 8 KB scratch

    scan_phase1<<<BLOCKS, TPB, 0, stream>>>((const int4*)tokens, ls, partials);
    scan_phase2<<<1, TPB, 0, stream>>>(partials, tokens, ls, out);
}